// Round 1
// 210.902 us; speedup vs baseline: 1.0004x; 1.0004x over previous
//
#include <hip/hip_runtime.h>

// Trilerp of 3 feature levels + mesh concat. Level-specialized waves:
//   lvl1 (64^3 x 32ch):  8 lanes/point  -> 8 points/wave
//   lvl2 (32^3 x 64ch): 16 lanes/point  -> 4 points/wave
//   lvl3 (16^3 x128ch): 32 lanes/point  -> 2 points/wave
// One grid; contiguous blockIdx ranges pick the level (wave-uniform branch).
//
// This revision attacks memory-latency serialization: the previous build
// allocated only 32 VGPRs, so the compiler HAD to serialize the 8 corner
// gathers (8 x float4 = 32 VGPRs of data alone) into load->wait->lerp
// groups, paying the ~900-cycle gather latency several times per wave.
//   - __launch_bounds__(256, 4): VGPR cap 128, allocator may keep all 8
//     corner loads live concurrently.
//   - sched_barrier(0) after the gathers: loads may not be sunk below the
//     lerp tree -> all 8 issue back-to-back, one latency per wave.
// Output layout: [B,N,227] = [32 | 64 | 128 | 3 mesh].

__device__ __forceinline__ int point_batch(int p, int N) {
    int b = 0;
    while (p >= N) { p -= N; ++b; }   // B is tiny (2)
    return b;
}

__device__ __forceinline__ float4 lerpw(const float4 a, const float4 b,
                                        float w, float w2) {
    float4 r;
    r.x = a.x * w + b.x * w2;
    r.y = a.y * w + b.y * w2;
    r.z = a.z * w + b.z * w2;
    r.w = a.w * w + b.w * w2;
    return r;
}

// D: grid dim; LPP: lanes per point (== C/4); OCB: output channel base.
template<int D, int LPP, int OCB>
__device__ __forceinline__ void do_level(const float4* __restrict__ fp,
                                         const float* __restrict__ coords,
                                         float* __restrict__ out,
                                         int pBase, int N, int P)
{
    const int tid  = threadIdx.x;
    const int lane = tid & 63;
    const int wv   = tid >> 6;
    const int p    = pBase + wv * (64 / LPP) + (lane / LPP);
    const int c4   = lane & (LPP - 1);
    if (p >= P) return;

    // coords: identical address within each LPP-lane group -> broadcast fetch
    const float cx = coords[p * 3 + 0];
    const float cy = coords[p * 3 + 1];
    const float cz = coords[p * 3 + 2];

    const float scale = (float)D;                    // 0.5^pow * 128 == D
    const float hi    = (float)((double)D - 1.01);   // matches Python

    const float ix = fminf(fmaxf(cx * scale, 0.01f), hi);
    const float iy = fminf(fmaxf(cy * scale, 0.01f), hi);
    const float iz = fminf(fmaxf(cz * scale, 0.01f), hi);

    const float x1f = floorf(ix), x2f = ceilf(ix);
    const float y1f = floorf(iy), y2f = ceilf(iy);
    const float z1f = floorf(iz), z2f = ceilf(iz);
    const int x1 = (int)x1f, x2 = (int)x2f;
    const int y1 = (int)y1f, y2 = (int)y2f;
    const int z1 = (int)z1f, z2 = (int)z2f;

    // Reference weight convention: wx multiplies the x2 (ceil) sample.
    const float wx = ix - x1f, wx2 = x2f - ix;
    const float wy = iy - y1f, wy2 = y2f - iy;
    const float wz = iz - z1f, wz2 = z2f - iz;

    const int base4 = point_batch(p, N) * (D * D * D * LPP) + c4;
    #define IDX(X, Y, Z) (base4 + (((X) * D + (Y)) * D + (Z)) * LPP)
    const float4 v111 = fp[IDX(x1, y1, z1)];
    const float4 v211 = fp[IDX(x2, y1, z1)];
    const float4 v121 = fp[IDX(x1, y2, z1)];
    const float4 v221 = fp[IDX(x2, y2, z1)];
    const float4 v112 = fp[IDX(x1, y1, z2)];
    const float4 v212 = fp[IDX(x2, y1, z2)];
    const float4 v122 = fp[IDX(x1, y2, z2)];
    const float4 v222 = fp[IDX(x2, y2, z2)];
    #undef IDX

    // Keep all 8 gathers issued before any lerp consumes them: one memory
    // round-trip per wave instead of several register-pressure-serialized ones.
    __builtin_amdgcn_sched_barrier(0);

    const float4 lx1a = lerpw(v211, v111, wx, wx2);
    const float4 lx2a = lerpw(v221, v121, wx, wx2);
    const float4 ly1  = lerpw(lx2a, lx1a, wy, wy2);
    const float4 lx1b = lerpw(v212, v112, wx, wx2);
    const float4 lx2b = lerpw(v222, v122, wx, wx2);
    const float4 ly2  = lerpw(lx2b, lx1b, wy, wy2);
    const float4 r    = lerpw(ly2,  ly1,  wz, wz2);

    float* o = out + p * 227 + OCB + c4 * 4;
    __builtin_nontemporal_store(r.x, o + 0);
    __builtin_nontemporal_store(r.y, o + 1);
    __builtin_nontemporal_store(r.z, o + 2);
    __builtin_nontemporal_store(r.w, o + 3);
}

__global__ __launch_bounds__(256, 4) void trilerp_kernel(
    const float* __restrict__ f1,      // [B,64,64,64,32]
    const float* __restrict__ f2,      // [B,32,32,32,64]
    const float* __restrict__ f3,      // [B,16,16,16,128]
    const float* __restrict__ coords,  // [B,N,3]
    const float* __restrict__ meshf,   // [B,N,3]
    float* __restrict__ out,           // [B,N,227]
    int N, int P, int nb1, int nb2, int nb3)
{
    const int blk = blockIdx.x;
    if (blk < nb1) {
        do_level<64, 8, 0>((const float4*)f1, coords, out, blk * 32, N, P);
    } else if (blk < nb1 + nb2) {
        do_level<32, 16, 32>((const float4*)f2, coords, out, (blk - nb1) * 16, N, P);
    } else if (blk < nb1 + nb2 + nb3) {
        do_level<16, 32, 96>((const float4*)f3, coords, out,
                             (blk - nb1 - nb2) * 8, N, P);
    } else {
        // mesh passthrough: one thread per element of [B,N,3]
        const int e = (blk - nb1 - nb2 - nb3) * 256 + (int)threadIdx.x;
        if (e < P * 3) {
            const int p = e / 3, c = e - p * 3;
            __builtin_nontemporal_store(meshf[e], &out[p * 227 + 224 + c]);
        }
    }
}

extern "C" void kernel_launch(void* const* d_in, const int* in_sizes, int n_in,
                              void* d_out, int out_size, void* d_ws, size_t ws_size,
                              hipStream_t stream) {
    const float* f1     = (const float*)d_in[1];
    const float* f2     = (const float*)d_in[2];
    const float* f3     = (const float*)d_in[3];
    const float* coords = (const float*)d_in[5];
    const float* meshf  = (const float*)d_in[6];
    float* out = (float*)d_out;

    const int B = in_sizes[1] / (64 * 64 * 64 * 32);
    const int N = in_sizes[5] / (B * 3);
    const int P = B * N;

    const int nb1 = (P + 31) / 32;          // 32 points/block (8 pts/wave)
    const int nb2 = (P + 15) / 16;          // 16 points/block
    const int nb3 = (P + 7) / 8;            //  8 points/block
    const int nbm = (P * 3 + 255) / 256;    // mesh copy blocks
    const int grid = nb1 + nb2 + nb3 + nbm;

    trilerp_kernel<<<dim3(grid), dim3(256), 0, stream>>>(
        f1, f2, f3, coords, meshf, out, N, P, nb1, nb2, nb3);
}

// Round 3
// 210.823 us; speedup vs baseline: 1.0008x; 1.0004x over previous
//
#include <hip/hip_runtime.h>

// Trilerp of 3 feature levels + mesh concat. Level-specialized waves:
//   lvl1 (64^3 x 32ch):  8 lanes/point  -> 8 points/wave
//   lvl2 (32^3 x 64ch): 16 lanes/point  -> 4 points/wave
//   lvl3 (16^3 x128ch): 32 lanes/point  -> 2 points/wave
// One grid; contiguous blockIdx ranges pick the level (wave-uniform branch).
//
// Round-1 lesson: launch_bounds + sched_barrier did NOT stop the compiler
// from register-pressure-serializing the 8 corner gathers (VGPR stayed 32,
// loads emitted as load->wait->lerp pairs; each wave pays the gather
// latency ~4x sequentially). This revision forces memory-level parallelism
// with volatile inline-asm gathers:
//   - 8x global_load_dwordx4 (SGPR base + 32-bit VGPR byte offset) issued
//     back-to-back (volatile asm keeps their order, distinct live dests),
//   - one s_waitcnt vmcnt(0), then sched_barrier(0) so the lerp tree cannot
//     be hoisted above the wait (register-only ops ignore "memory" clobber).
// ~56 VGPRs still allows 8 waves/SIMD -> MLP is free in occupancy terms;
// pinned via __launch_bounds__(256, 8).
// (Round 2 was a broker GPUAcquisitionTimeout; this is the same kernel
// resubmitted -- it was never measured.)
// Output layout: [B,N,227] = [32 | 64 | 128 | 3 mesh].

typedef float floatx4 __attribute__((ext_vector_type(4)));

__device__ __forceinline__ int point_batch(int p, int N) {
    int b = 0;
    while (p >= N) { p -= N; ++b; }   // B is tiny (2)
    return b;
}

// D: grid dim; LPP: lanes per point (== C/4); OCB: output channel base.
template<int D, int LPP, int OCB>
__device__ __forceinline__ void do_level(const float* __restrict__ fbase,
                                         const float* __restrict__ coords,
                                         float* __restrict__ out,
                                         int pBase, int N, int P)
{
    const int tid  = threadIdx.x;
    const int lane = tid & 63;
    const int wv   = tid >> 6;
    const int p    = pBase + wv * (64 / LPP) + (lane / LPP);
    const int c4   = lane & (LPP - 1);
    if (p >= P) return;

    // coords: identical address within each LPP-lane group -> broadcast fetch
    const float cx = coords[p * 3 + 0];
    const float cy = coords[p * 3 + 1];
    const float cz = coords[p * 3 + 2];

    const float scale = (float)D;                    // 0.5^pow * 128 == D
    const float hi    = (float)((double)D - 1.01);   // matches Python

    const float ix = fminf(fmaxf(cx * scale, 0.01f), hi);
    const float iy = fminf(fmaxf(cy * scale, 0.01f), hi);
    const float iz = fminf(fmaxf(cz * scale, 0.01f), hi);

    const float x1f = floorf(ix), x2f = ceilf(ix);
    const float y1f = floorf(iy), y2f = ceilf(iy);
    const float z1f = floorf(iz), z2f = ceilf(iz);
    const int x1 = (int)x1f, x2 = (int)x2f;
    const int y1 = (int)y1f, y2 = (int)y2f;
    const int z1 = (int)z1f, z2 = (int)z2f;

    // Reference weight convention: wx multiplies the x2 (ceil) sample.
    const float wx = ix - x1f, wx2 = x2f - ix;
    const float wy = iy - y1f, wy2 = y2f - iy;
    const float wz = iz - z1f, wz2 = z2f - iz;

    // Byte offsets from the level base pointer. Max (lvl1, B=2):
    // 2 * 64^3 * 32ch * 4B = 67 MB -- fits 32-bit unsigned offset.
    const unsigned baseB = (unsigned)point_batch(p, N) * (unsigned)(D * D * D * LPP * 16)
                         + (unsigned)c4 * 16u;
    #define OFFB(X, Y, Z) (baseB + (unsigned)((((X) * D + (Y)) * D + (Z)) * LPP) * 16u)

    floatx4 v111, v211, v121, v221, v112, v212, v122, v222;
    // 8 gathers issued back-to-back, all in flight simultaneously.
    asm volatile("global_load_dwordx4 %0, %1, %2"
                 : "=v"(v111) : "v"(OFFB(x1, y1, z1)), "s"(fbase));
    asm volatile("global_load_dwordx4 %0, %1, %2"
                 : "=v"(v211) : "v"(OFFB(x2, y1, z1)), "s"(fbase));
    asm volatile("global_load_dwordx4 %0, %1, %2"
                 : "=v"(v121) : "v"(OFFB(x1, y2, z1)), "s"(fbase));
    asm volatile("global_load_dwordx4 %0, %1, %2"
                 : "=v"(v221) : "v"(OFFB(x2, y2, z1)), "s"(fbase));
    asm volatile("global_load_dwordx4 %0, %1, %2"
                 : "=v"(v112) : "v"(OFFB(x1, y1, z2)), "s"(fbase));
    asm volatile("global_load_dwordx4 %0, %1, %2"
                 : "=v"(v212) : "v"(OFFB(x2, y1, z2)), "s"(fbase));
    asm volatile("global_load_dwordx4 %0, %1, %2"
                 : "=v"(v122) : "v"(OFFB(x1, y2, z2)), "s"(fbase));
    asm volatile("global_load_dwordx4 %0, %1, %2"
                 : "=v"(v222) : "v"(OFFB(x2, y2, z2)), "s"(fbase));
    #undef OFFB

    // One memory round-trip per wave. sched_barrier: lerps must not be
    // hoisted above the wait (data-dep alone orders them after the LOADS,
    // not after the WAIT).
    asm volatile("s_waitcnt vmcnt(0)");
    __builtin_amdgcn_sched_barrier(0);

    const floatx4 lx1a = v211 * wx + v111 * wx2;
    const floatx4 lx2a = v221 * wx + v121 * wx2;
    const floatx4 ly1  = lx2a * wy + lx1a * wy2;
    const floatx4 lx1b = v212 * wx + v112 * wx2;
    const floatx4 lx2b = v222 * wx + v122 * wx2;
    const floatx4 ly2  = lx2b * wy + lx1b * wy2;
    const floatx4 r    = ly2  * wz + ly1  * wz2;

    float* o = out + p * 227 + OCB + c4 * 4;
    __builtin_nontemporal_store(r.x, o + 0);
    __builtin_nontemporal_store(r.y, o + 1);
    __builtin_nontemporal_store(r.z, o + 2);
    __builtin_nontemporal_store(r.w, o + 3);
}

__global__ __launch_bounds__(256, 8) void trilerp_kernel(
    const float* __restrict__ f1,      // [B,64,64,64,32]
    const float* __restrict__ f2,      // [B,32,32,32,64]
    const float* __restrict__ f3,      // [B,16,16,16,128]
    const float* __restrict__ coords,  // [B,N,3]
    const float* __restrict__ meshf,   // [B,N,3]
    float* __restrict__ out,           // [B,N,227]
    int N, int P, int nb1, int nb2, int nb3)
{
    const int blk = blockIdx.x;
    if (blk < nb1) {
        do_level<64, 8, 0>(f1, coords, out, blk * 32, N, P);
    } else if (blk < nb1 + nb2) {
        do_level<32, 16, 32>(f2, coords, out, (blk - nb1) * 16, N, P);
    } else if (blk < nb1 + nb2 + nb3) {
        do_level<16, 32, 96>(f3, coords, out, (blk - nb1 - nb2) * 8, N, P);
    } else {
        // mesh passthrough: one thread per element of [B,N,3]
        const int e = (blk - nb1 - nb2 - nb3) * 256 + (int)threadIdx.x;
        if (e < P * 3) {
            const int p = e / 3, c = e - p * 3;
            __builtin_nontemporal_store(meshf[e], &out[p * 227 + 224 + c]);
        }
    }
}

extern "C" void kernel_launch(void* const* d_in, const int* in_sizes, int n_in,
                              void* d_out, int out_size, void* d_ws, size_t ws_size,
                              hipStream_t stream) {
    const float* f1     = (const float*)d_in[1];
    const float* f2     = (const float*)d_in[2];
    const float* f3     = (const float*)d_in[3];
    const float* coords = (const float*)d_in[5];
    const float* meshf  = (const float*)d_in[6];
    float* out = (float*)d_out;

    const int B = in_sizes[1] / (64 * 64 * 64 * 32);
    const int N = in_sizes[5] / (B * 3);
    const int P = B * N;

    const int nb1 = (P + 31) / 32;          // 32 points/block (8 pts/wave)
    const int nb2 = (P + 15) / 16;          // 16 points/block
    const int nb3 = (P + 7) / 8;            //  8 points/block
    const int nbm = (P * 3 + 255) / 256;    // mesh copy blocks
    const int grid = nb1 + nb2 + nb3 + nbm;

    trilerp_kernel<<<dim3(grid), dim3(256), 0, stream>>>(
        f1, f2, f3, coords, meshf, out, N, P, nb1, nb2, nb3);
}